// Round 1
// 551.933 us; speedup vs baseline: 1.0907x; 1.0907x over previous
//
#include <hip/hip_runtime.h>

typedef unsigned short u16;
typedef __bf16 bf16x8 __attribute__((ext_vector_type(8)));
typedef float f32x4 __attribute__((ext_vector_type(4)));
typedef u16 u16x8 __attribute__((ext_vector_type(8)));

#define M_DIM 8192
#define N_DIM 4096
#define K_DIM 4096
#define BM 256
#define BN 256
#define BK 64
#define NT (K_DIM / BK)  // 64 K-tiles

__device__ __forceinline__ u16 f2b(float f) {
  unsigned int x = __float_as_uint(f);
  unsigned int r = (x + 0x7fffu + ((x >> 16) & 1u)) >> 16;
  return (u16)r;
}

#define GLOAD_LDS16(gp, lp)                                        \
  __builtin_amdgcn_global_load_lds(                                \
      (const __attribute__((address_space(1))) void*)(gp),         \
      (__attribute__((address_space(3))) void*)(lp), 16, 0, 0)

#define SB0 __builtin_amdgcn_sched_barrier(0)
#define BAR                                                        \
  do {                                                             \
    SB0;                                                           \
    __builtin_amdgcn_s_barrier();                                  \
    SB0;                                                           \
  } while (0)
#define VMW(N)                                                     \
  do {                                                             \
    SB0;                                                           \
    asm volatile("s_waitcnt vmcnt(" #N ")" ::: "memory");          \
    SB0;                                                           \
  } while (0)

// ---------------------------------------------------------------------------
// Kernel 0: convert x fp32 -> bf16. 8 elements / thread. (unchanged)
// ---------------------------------------------------------------------------
__global__ __launch_bounds__(256) void cvt_x(const float* __restrict__ X,
                                             u16* __restrict__ Xb) {
  const size_t t = (size_t)blockIdx.x * 256 + threadIdx.x;
  const f32x4* src = (const f32x4*)X + t * 2;
  f32x4 a = src[0];
  f32x4 b = src[1];
  u16x8 o;
  o[0] = f2b(a[0]); o[1] = f2b(a[1]); o[2] = f2b(a[2]); o[3] = f2b(a[3]);
  o[4] = f2b(b[0]); o[5] = f2b(b[1]); o[6] = f2b(b[2]); o[7] = f2b(b[3]);
  *((u16x8*)Xb + t) = o;
}

// ---------------------------------------------------------------------------
// Kernel 1: Weff build (unchanged — ~roofline for its traffic)
// ---------------------------------------------------------------------------
__global__ __launch_bounds__(256) void build_weff(
    const float* __restrict__ W, const float* __restrict__ Au,
    const float* __restrict__ Bu, const float* __restrict__ A0,
    const float* __restrict__ B0, u16* __restrict__ Weff) {
  __shared__ float coef[64 * 16];  // coef[r][oi]
  const int t = threadIdx.x;
  const int o0 = blockIdx.y * 16;

#pragma unroll
  for (int j = 0; j < 4; j++) {
    const int idx = t + j * 256;     // 0..1023
    const int r = idx >> 4;          // 0..63
    const int oi = idx & 15;
    const int o = o0 + oi;
    float v;
    if (r < 8) {
      v = Bu[o * 8 + r];
    } else {
      const int rs = r - 8;
      if (o < 2048) {
        v = B0[o * 56 + rs];
      } else {
        const int rr = rs ? (rs - 1) : 55;
        v = B0[(o - 2048) * 56 + rr];
      }
    }
    coef[r * 16 + oi] = v;
  }
  __syncthreads();

  const int d0 = blockIdx.x * 1024 + t * 4;
  const int hi = (d0 >= 2048);
  const int dd = hi ? (d0 - 2048) : d0;

  f32x4 acc[16] = {};

#pragma unroll
  for (int r = 0; r < 8; r++) {
    f32x4 a = *(const f32x4*)(Au + (size_t)r * 4096 + d0);
    const float* cr = &coef[r * 16];
#pragma unroll
    for (int oi = 0; oi < 16; oi++) {
      const float c = cr[oi];
      acc[oi][0] += c * a[0]; acc[oi][1] += c * a[1];
      acc[oi][2] += c * a[2]; acc[oi][3] += c * a[3];
    }
  }
#pragma unroll 4
  for (int rs = 0; rs < 56; rs++) {
    const int rr = hi ? (rs ? (rs - 1) : 55) : rs;
    f32x4 a = *(const f32x4*)(A0 + (size_t)rr * 2048 + dd);
    const float* cr = &coef[(rs + 8) * 16];
#pragma unroll
    for (int oi = 0; oi < 16; oi++) {
      const float c = cr[oi];
      acc[oi][0] += c * a[0]; acc[oi][1] += c * a[1];
      acc[oi][2] += c * a[2]; acc[oi][3] += c * a[3];
    }
  }

#pragma unroll
  for (int oi = 0; oi < 16; oi++) {
    f32x4 w = *(const f32x4*)(W + (size_t)(o0 + oi) * 4096 + d0);
    ushort4 ov;
    ov.x = f2b(acc[oi][0] + w[0]);
    ov.y = f2b(acc[oi][1] + w[1]);
    ov.z = f2b(acc[oi][2] + w[2]);
    ov.w = f2b(acc[oi][3] + w[3]);
    *(ushort4*)(Weff + (size_t)(o0 + oi) * 4096 + d0) = ov;
  }
}

// ---------------------------------------------------------------------------
// Kernel 2: C[m][n] = sum_k Xb[m][k]*Weff[n][k] + bias[n]   (bf16 MFMA, NT)
//
// 256x256 8-phase template (T1+T2+T3+T4+T5):
//  - 8 waves (2M x 4N), per-wave 128x64 output, acc[8][4] f32x4.
//  - BK=64, double-buffered LDS 128 KiB: A[2][256][64] | B[2][256][64].
//  - T2 swizzle: read byte ^= ((row&7)<<4); inverse pre-applied to the
//    per-lane GLOBAL source (linear LDS dest — rule #21 both-sides).
//  - 4 phases / K-tile, each {ds_read frags; 2x global_load_lds; barrier;
//    setprio(1) 16 MFMA setprio(0); barrier}. Counted waits: vmcnt(6) end
//    of phase B, vmcnt(4) end of phase D — never 0 in the main loop.
//  - Stage groups for tile T (2 gloads each): r02(T) @ phase D(T-2),
//    b01(T) @ A(T-1), b23(T) @ B(T-1), r13(T) @ C(T-1). Every group has
//    >=3 phases issue->need gap; every LDS region re-staged only after a
//    barrier that follows its last read (checked per wm/wn ownership).
//  - Tail: tile index clamped to NT-1 so per-wave vmcnt counts stay
//    uniform (duplicate loads land in the already-consumed buffer).
// ---------------------------------------------------------------------------
__global__ __launch_bounds__(512, 2) void gemm_bt_bias(
    const u16* __restrict__ X, const u16* __restrict__ Wf,
    const float* __restrict__ bias, float* __restrict__ C) {
  __shared__ __align__(16) u16 lds[65536];  // 128 KiB

  const int tid = threadIdx.x;
  const int wave = tid >> 6;
  const int lane = tid & 63;
  const int wm = wave >> 2;    // 0..1
  const int wn = wave & 3;     // 0..3
  const int quad = lane >> 4;  // 0..3
  const int l16 = lane & 15;

  // T1: XCD-aware swizzle. 512 blocks, 64 contiguous logical tiles per XCD,
  // n-fastest so neighbors share the A (X) panel in L2.
  const int wgid = ((blockIdx.x & 7) << 6) | (blockIdx.x >> 3);
  const int n0 = (wgid & 15) * BN;  // 16 n-tiles
  const int m0 = (wgid >> 4) * BM;  // 32 m-tiles

  // Staging addressing: LDS dest is linear (wave-uniform base + lane*16);
  // global source carries the inverse T2 swizzle: colblock = (l&7)^(l>>3).
  const int srow = lane >> 3;           // 0..7
  const int sq = lane & 7;              // physical colblock
  const int scol = ((sq ^ srow) << 3);  // pre-swizzled source column (elems)
  const u16* xg = X + (size_t)(m0 + wave * 8 + srow) * K_DIM + scol;
  const u16* wg = Wf + (size_t)(n0 + wave * 8 + srow) * K_DIM + scol;
  u16* lA = lds + wave * 512;           // wave-uniform
  u16* lB = lds + 32768 + wave * 512;

#define SG_A(b, r, t)                                                       \
  GLOAD_LDS16(xg + (size_t)(r) * 64 * K_DIM + (size_t)(t) * BK,             \
              lA + (b) * 16384 + (r) * 4096)
#define SG_B(b, r, t)                                                       \
  GLOAD_LDS16(wg + (size_t)(r) * 64 * K_DIM + (size_t)(t) * BK,             \
              lB + (b) * 16384 + (r) * 4096)

  f32x4 acc[8][4] = {};
  bf16x8 afr[4][2];     // A frags for current m-half (mi, k)
  bf16x8 bfr[2][2][2];  // B frags, both n-halves live (nh, ni, k)

  // T2 read swizzle: phys = (cb*16) ^ ((row&7)<<4); row&7 == l16&7 always.
  const int c0 = (quad << 4) ^ ((l16 & 7) << 4);

#define READ_A(mh)                                                          \
  do {                                                                      \
    const char* ab_ = Ab + (size_t)((wm * 128 + (mh) * 64 + l16) * 128);    \
    _Pragma("unroll") for (int mi = 0; mi < 4; mi++) {                      \
      afr[mi][0] = *(const bf16x8*)(ab_ + mi * 2048 + c0);                  \
      afr[mi][1] = *(const bf16x8*)(ab_ + mi * 2048 + (c0 ^ 64));           \
    }                                                                       \
  } while (0)

#define READ_B(nh)                                                          \
  do {                                                                      \
    const char* bb_ = Bb + (size_t)((wn * 64 + (nh) * 32 + l16) * 128);     \
    _Pragma("unroll") for (int ni = 0; ni < 2; ni++) {                      \
      bfr[nh][ni][0] = *(const bf16x8*)(bb_ + ni * 2048 + c0);              \
      bfr[nh][ni][1] = *(const bf16x8*)(bb_ + ni * 2048 + (c0 ^ 64));       \
    }                                                                       \
  } while (0)

#define MFMA_Q(mh, nh)                                                      \
  do {                                                                      \
    __builtin_amdgcn_s_setprio(1);                                          \
    _Pragma("unroll") for (int mi = 0; mi < 4; mi++) {                      \
      _Pragma("unroll") for (int ni = 0; ni < 2; ni++) {                    \
        acc[(mh)*4 + mi][(nh)*2 + ni] =                                     \
            __builtin_amdgcn_mfma_f32_16x16x32_bf16(                        \
                afr[mi][0], bfr[nh][ni][0],                                 \
                acc[(mh)*4 + mi][(nh)*2 + ni], 0, 0, 0);                    \
        acc[(mh)*4 + mi][(nh)*2 + ni] =                                     \
            __builtin_amdgcn_mfma_f32_16x16x32_bf16(                        \
                afr[mi][1], bfr[nh][ni][1],                                 \
                acc[(mh)*4 + mi][(nh)*2 + ni], 0, 0, 0);                    \
      }                                                                     \
    }                                                                       \
    __builtin_amdgcn_s_setprio(0);                                          \
  } while (0)

  // Prologue: stage tile 0 fully + r02(1). After VMW(4): r02(0), b01(0),
  // b23(0) landed (exactly what phases A/B of t=0 read); r13(0)+r02(1) may
  // remain in flight (r13(0) is guarded by the first VMW(6)).
  SG_A(0, 0, 0); SG_A(0, 2, 0);  // r02(0)
  SG_B(0, 0, 0); SG_B(0, 1, 0);  // b01(0)
  SG_B(0, 2, 0); SG_B(0, 3, 0);  // b23(0)
  SG_A(0, 1, 0); SG_A(0, 3, 0);  // r13(0)
  SG_A(1, 0, 1); SG_A(1, 2, 1);  // r02(1)
  VMW(4);
  BAR;

  for (int t = 0; t < NT; ++t) {
    const int buf = t & 1;
    const char* Ab = (const char*)lds + buf * 32768;
    const char* Bb = (const char*)lds + 65536 + buf * 32768;
    const int t1 = (t + 1 < NT) ? t + 1 : NT - 1;
    const int t2 = (t + 2 < NT) ? t + 2 : NT - 1;
    const int b1 = (t + 1) & 1;
    const int b2 = buf;  // (t+2)&1

    // Phase A: frags A[mh0], B[nh0] of tile t; stage b01(t+1); MFMA mh0xnh0.
    READ_A(0);
    READ_B(0);
    SG_B(b1, 0, t1); SG_B(b1, 1, t1);
    BAR;
    MFMA_Q(0, 0);
    BAR;

    // Phase B: frags B[nh1]; stage b23(t+1); MFMA mh0xnh1; wait r13(t).
    READ_B(1);
    SG_B(b1, 2, t1); SG_B(b1, 3, t1);
    BAR;
    MFMA_Q(0, 1);
    VMW(6);  // leaves b23(t+1), b01(t+1), r02(t+1) in flight; r13(t) landed
    BAR;

    // Phase C: frags A[mh1]; stage r13(t+1); MFMA mh1xnh1.
    READ_A(1);
    SG_A(b1, 1, t1); SG_A(b1, 3, t1);
    BAR;
    MFMA_Q(1, 1);
    BAR;

    // Phase D: stage r02(t+2) (rows 0-63/128-191 of buf, last read in
    // phase A — barrier-protected); MFMA mh1xnh0 (regs only); wait so all
    // of tile t+1 except r13/r02-next is landed.
    SG_A(b2, 0, t2); SG_A(b2, 2, t2);
    BAR;
    MFMA_Q(1, 0);
    VMW(4);  // leaves r02(t+2), r13(t+1) in flight; b01/b23(t+1) landed
    BAR;
  }
  VMW(0);  // drain DMA before LDS goes out of scope

  // Epilogue: C/D layout col=l16 (from B-frag j), row=quad*4+reg (A-frag i).
#pragma unroll
  for (int j = 0; j < 4; j++) {
    const int col = n0 + wn * 64 + j * 16 + l16;
    const float bv = bias[col];
#pragma unroll
    for (int i = 0; i < 8; i++) {
      const int row = m0 + wm * 128 + i * 16 + quad * 4;
#pragma unroll
      for (int r = 0; r < 4; r++) {
        C[(size_t)(row + r) * N_DIM + col] = acc[i][j][r] + bv;
      }
    }
  }
}

extern "C" void kernel_launch(void* const* d_in, const int* in_sizes, int n_in,
                              void* d_out, int out_size, void* d_ws, size_t ws_size,
                              hipStream_t stream) {
  const float* x  = (const float*)d_in[0];  // [4,2048,4096] fp32
  const float* W  = (const float*)d_in[1];  // [4096,4096] fp32
  const float* b  = (const float*)d_in[2];  // [4096] fp32
  const float* Au = (const float*)d_in[3];  // [8,4096] fp32
  const float* Bu = (const float*)d_in[4];  // [4096,8] fp32
  const float* A0 = (const float*)d_in[5];  // [56,2048] fp32
  const float* B0 = (const float*)d_in[6];  // [2048,56] fp32
  float* out = (float*)d_out;               // [4,2048,4096] fp32

  u16* Xb   = (u16*)d_ws;                                      // 64 MB
  u16* Weff = (u16*)((char*)d_ws + (size_t)64 * 1024 * 1024);  // 32 MB

  cvt_x<<<16384, 256, 0, stream>>>(x, Xb);
  build_weff<<<dim3(4, 256), 256, 0, stream>>>(W, Au, Bu, A0, B0, Weff);
  gemm_bt_bias<<<dim3(512), dim3(512), 0, stream>>>(Xb, Weff, b, out);
}

// Round 3
// 551.045 us; speedup vs baseline: 1.0925x; 1.0016x over previous
//
#include <hip/hip_runtime.h>

typedef unsigned short u16;
typedef __bf16 bf16x8 __attribute__((ext_vector_type(8)));
typedef float f32x4 __attribute__((ext_vector_type(4)));
typedef u16 u16x8 __attribute__((ext_vector_type(8)));

#define M_DIM 8192
#define N_DIM 4096
#define K_DIM 4096
#define BM 256
#define BN 256
#define BK 64
#define NT (K_DIM / BK)  // 64 K-tiles

__device__ __forceinline__ u16 f2b(float f) {
  unsigned int x = __float_as_uint(f);
  unsigned int r = (x + 0x7fffu + ((x >> 16) & 1u)) >> 16;
  return (u16)r;
}

#define GLOAD_LDS16(gp, lp)                                        \
  __builtin_amdgcn_global_load_lds(                                \
      (const __attribute__((address_space(1))) void*)(gp),         \
      (__attribute__((address_space(3))) void*)(lp), 16, 0, 0)

#define BAR __builtin_amdgcn_s_barrier()
// Counted vmem wait + rule-#18 fence: nothing may be scheduled upward
// across the wait (protects the LDS reads that follow it).
#define VMW(N)                                                     \
  do {                                                             \
    asm volatile("s_waitcnt vmcnt(" #N ")" ::: "memory");          \
    __builtin_amdgcn_sched_barrier(0);                             \
  } while (0)

// ---------------------------------------------------------------------------
// Kernel 0: convert x fp32 -> bf16. 8 elements / thread. (unchanged)
// ---------------------------------------------------------------------------
__global__ __launch_bounds__(256) void cvt_x(const float* __restrict__ X,
                                             u16* __restrict__ Xb) {
  const size_t t = (size_t)blockIdx.x * 256 + threadIdx.x;
  const f32x4* src = (const f32x4*)X + t * 2;
  f32x4 a = src[0];
  f32x4 b = src[1];
  u16x8 o;
  o[0] = f2b(a[0]); o[1] = f2b(a[1]); o[2] = f2b(a[2]); o[3] = f2b(a[3]);
  o[4] = f2b(b[0]); o[5] = f2b(b[1]); o[6] = f2b(b[2]); o[7] = f2b(b[3]);
  *((u16x8*)Xb + t) = o;
}

// ---------------------------------------------------------------------------
// Kernel 1: Weff build (unchanged)
// ---------------------------------------------------------------------------
__global__ __launch_bounds__(256) void build_weff(
    const float* __restrict__ W, const float* __restrict__ Au,
    const float* __restrict__ Bu, const float* __restrict__ A0,
    const float* __restrict__ B0, u16* __restrict__ Weff) {
  __shared__ float coef[64 * 16];  // coef[r][oi]
  const int t = threadIdx.x;
  const int o0 = blockIdx.y * 16;

#pragma unroll
  for (int j = 0; j < 4; j++) {
    const int idx = t + j * 256;     // 0..1023
    const int r = idx >> 4;          // 0..63
    const int oi = idx & 15;
    const int o = o0 + oi;
    float v;
    if (r < 8) {
      v = Bu[o * 8 + r];
    } else {
      const int rs = r - 8;
      if (o < 2048) {
        v = B0[o * 56 + rs];
      } else {
        const int rr = rs ? (rs - 1) : 55;
        v = B0[(o - 2048) * 56 + rr];
      }
    }
    coef[r * 16 + oi] = v;
  }
  __syncthreads();

  const int d0 = blockIdx.x * 1024 + t * 4;
  const int hi = (d0 >= 2048);
  const int dd = hi ? (d0 - 2048) : d0;

  f32x4 acc[16] = {};

#pragma unroll
  for (int r = 0; r < 8; r++) {
    f32x4 a = *(const f32x4*)(Au + (size_t)r * 4096 + d0);
    const float* cr = &coef[r * 16];
#pragma unroll
    for (int oi = 0; oi < 16; oi++) {
      const float c = cr[oi];
      acc[oi][0] += c * a[0]; acc[oi][1] += c * a[1];
      acc[oi][2] += c * a[2]; acc[oi][3] += c * a[3];
    }
  }
#pragma unroll 4
  for (int rs = 0; rs < 56; rs++) {
    const int rr = hi ? (rs ? (rs - 1) : 55) : rs;
    f32x4 a = *(const f32x4*)(A0 + (size_t)rr * 2048 + dd);
    const float* cr = &coef[(rs + 8) * 16];
#pragma unroll
    for (int oi = 0; oi < 16; oi++) {
      const float c = cr[oi];
      acc[oi][0] += c * a[0]; acc[oi][1] += c * a[1];
      acc[oi][2] += c * a[2]; acc[oi][3] += c * a[3];
    }
  }

#pragma unroll
  for (int oi = 0; oi < 16; oi++) {
    f32x4 w = *(const f32x4*)(W + (size_t)(o0 + oi) * 4096 + d0);
    ushort4 ov;
    ov.x = f2b(acc[oi][0] + w[0]);
    ov.y = f2b(acc[oi][1] + w[1]);
    ov.z = f2b(acc[oi][2] + w[2]);
    ov.w = f2b(acc[oi][3] + w[3]);
    *(ushort4*)(Weff + (size_t)(o0 + oi) * 4096 + d0) = ov;
  }
}

// ---------------------------------------------------------------------------
// Kernel 2: C[m][n] = sum_k Xb[m][k]*Weff[n][k] + bias[n]   (bf16 MFMA, NT)
//
// 256x256 8-phase + one-phase-ahead register pipeline:
//  - Quadrant order (0,0),(0,1),(1,1),(1,0). Shared afr (A-half) and split
//    bfr (both B-halves) are reloaded strictly AFTER their last MFMA use,
//    so every MFMA cluster's operands were ds_read >=1 barrier earlier:
//      B(t) tail:  READ A1(t)            -> feeds C(t), D(t)
//      D(t) tail:  READ A0,B0,B1 (t+1)   -> feeds A(t+1), B(t+1)
//  - Counted waits: VMW(4)@endA (drains r13(t) before B-tail reads it),
//    VMW(4)@endD (drains b01/b23/r02(t+1) before D-tail reads).
//    Never vmcnt(0) in the loop. Each VMW carries a sched_barrier(0)
//    fence (rule #18) so no ds_read is hoisted above the wait.
//  - Stage groups (2 gloads each): b01(t+1)@A, b23(t+1)@B, r13(t+1)@C,
//    r02(t+2)@D. Write-after-read distance >=4 barriers for every region.
//  - vmcnt ledger (per wave, loop top): [r13(t), r02(t+1)] = 4 in flight.
//    A:+2 VMW(4) drains r13(t). B:+2. C:+2. D:+2 VMW(4) drains
//    b01/b23/r02(t+1), leaving [r13(t+1), r02(t+2)] = 4. Invariant holds.
//  - T2 swizzle: read byte ^= ((row&7)<<4); inverse pre-applied to the
//    per-lane GLOBAL source (linear LDS dest).
// ---------------------------------------------------------------------------
__global__ __launch_bounds__(512, 2) void gemm_bt_bias(
    const u16* __restrict__ X, const u16* __restrict__ Wf,
    const float* __restrict__ bias, float* __restrict__ C) {
  __shared__ __align__(16) u16 lds[65536];  // 128 KiB

  const int tid = threadIdx.x;
  const int wave = tid >> 6;
  const int lane = tid & 63;
  const int wm = wave >> 2;    // 0..1
  const int wn = wave & 3;     // 0..3
  const int quad = lane >> 4;  // 0..3
  const int l16 = lane & 15;

  // T1: XCD-aware swizzle (512 blocks, 64 per XCD, n-fastest).
  const int wgid = ((blockIdx.x & 7) << 6) | (blockIdx.x >> 3);
  const int n0 = (wgid & 15) * BN;  // 16 n-tiles
  const int m0 = (wgid >> 4) * BM;  // 32 m-tiles

  // Staging: linear LDS dest (wave-uniform base + lane*16); global source
  // carries the inverse T2 swizzle: colblock = (l&7)^(l>>3).
  const int srow = lane >> 3;           // 0..7
  const int sq = lane & 7;              // physical colblock
  const int scol = ((sq ^ srow) << 3);  // pre-swizzled source column (elems)
  const u16* xg = X + (size_t)(m0 + wave * 8 + srow) * K_DIM + scol;
  const u16* wg = Wf + (size_t)(n0 + wave * 8 + srow) * K_DIM + scol;
  u16* lA = lds + wave * 512;           // wave-uniform
  u16* lB = lds + 32768 + wave * 512;

#define SG_A(b, r, t)                                                       \
  GLOAD_LDS16(xg + (size_t)(r) * 64 * K_DIM + (size_t)(t) * BK,             \
              lA + (b) * 16384 + (r) * 4096)
#define SG_B(b, r, t)                                                       \
  GLOAD_LDS16(wg + (size_t)(r) * 64 * K_DIM + (size_t)(t) * BK,             \
              lB + (b) * 16384 + (r) * 4096)

  f32x4 acc[8][4] = {};
  bf16x8 afr[4][2];     // A frags, one m-half live at a time
  bf16x8 bfr[2][2][2];  // B frags, both n-halves live (nh, ni, k)

  // T2 read swizzle: phys = (cb*16) ^ ((row&7)<<4); row&7 == l16&7 always.
  const int c0 = (quad << 4) ^ ((l16 & 7) << 4);

#define READ_A(mh, ABASE)                                                   \
  do {                                                                      \
    const char* ab_ =                                                       \
        (ABASE) + (size_t)((wm * 128 + (mh) * 64 + l16) * 128);             \
    _Pragma("unroll") for (int mi = 0; mi < 4; mi++) {                      \
      afr[mi][0] = *(const bf16x8*)(ab_ + mi * 2048 + c0);                  \
      afr[mi][1] = *(const bf16x8*)(ab_ + mi * 2048 + (c0 ^ 64));           \
    }                                                                       \
  } while (0)

#define READ_B(nh, BBASE)                                                   \
  do {                                                                      \
    const char* bb_ =                                                       \
        (BBASE) + (size_t)((wn * 64 + (nh) * 32 + l16) * 128);              \
    _Pragma("unroll") for (int ni = 0; ni < 2; ni++) {                      \
      bfr[nh][ni][0] = *(const bf16x8*)(bb_ + ni * 2048 + c0);              \
      bfr[nh][ni][1] = *(const bf16x8*)(bb_ + ni * 2048 + (c0 ^ 64));       \
    }                                                                       \
  } while (0)

#define MFMA_Q(mh, nh)                                                      \
  do {                                                                      \
    __builtin_amdgcn_s_setprio(1);                                          \
    _Pragma("unroll") for (int mi = 0; mi < 4; mi++) {                      \
      _Pragma("unroll") for (int ni = 0; ni < 2; ni++) {                    \
        acc[(mh)*4 + mi][(nh)*2 + ni] =                                     \
            __builtin_amdgcn_mfma_f32_16x16x32_bf16(                        \
                afr[mi][0], bfr[nh][ni][0],                                 \
                acc[(mh)*4 + mi][(nh)*2 + ni], 0, 0, 0);                    \
        acc[(mh)*4 + mi][(nh)*2 + ni] =                                     \
            __builtin_amdgcn_mfma_f32_16x16x32_bf16(                        \
                afr[mi][1], bfr[nh][ni][1],                                 \
                acc[(mh)*4 + mi][(nh)*2 + ni], 0, 0, 0);                    \
      }                                                                     \
    }                                                                       \
    __builtin_amdgcn_s_setprio(0);                                          \
  } while (0)

  // Prologue: stage tile 0 + r02(1). VMW(4) leaves [r13(0), r02(1)] in
  // flight -> r02(0), b01(0), b23(0) landed; then pre-read A0,B0,B1 of t=0.
  SG_A(0, 0, 0); SG_A(0, 2, 0);  // r02(0)
  SG_B(0, 0, 0); SG_B(0, 1, 0);  // b01(0)
  SG_B(0, 2, 0); SG_B(0, 3, 0);  // b23(0)
  SG_A(0, 1, 0); SG_A(0, 3, 0);  // r13(0)
  SG_A(1, 0, 1); SG_A(1, 2, 1);  // r02(1)
  VMW(4);
  BAR;
  {
    const char* Ab0 = (const char*)lds;
    const char* Bb0 = (const char*)lds + 65536;
    READ_A(0, Ab0);
    READ_B(0, Bb0);
    READ_B(1, Bb0);
  }

  for (int t = 0; t < NT; ++t) {
    const int buf = t & 1;
    const char* Ab = (const char*)lds + buf * 32768;
    const int t1 = (t + 1 < NT) ? t + 1 : NT - 1;
    const int t2 = (t + 2 < NT) ? t + 2 : NT - 1;
    const int b1 = (t + 1) & 1;
    const int b2 = buf;  // (t+2)&1

    // Phase A: stage b01(t+1); MFMA(0,0) (operands from D(t-1) tail);
    // VMW(4) drains r13(t) (issued C(t-1)) before the endA barrier.
    SG_B(b1, 0, t1); SG_B(b1, 1, t1);
    BAR;
    MFMA_Q(0, 0);
    VMW(4);
    BAR;

    // Phase B: stage b23(t+1); MFMA(0,1); tail-read A1(t) (r13 landed).
    SG_B(b1, 2, t1); SG_B(b1, 3, t1);
    BAR;
    MFMA_Q(0, 1);
    READ_A(1, Ab);
    BAR;

    // Phase C: stage r13(t+1); MFMA(1,1) (A1 read last phase).
    SG_A(b1, 1, t1); SG_A(b1, 3, t1);
    BAR;
    MFMA_Q(1, 1);
    BAR;

    // Phase D: stage r02(t+2) into current buf (region's last read was
    // D(t-1) tail — >=4 barriers ago); MFMA(1,0); VMW(4) drains
    // b01/b23/r02(t+1); then tail-read next tile's A0,B0,B1.
    SG_A(b2, 0, t2); SG_A(b2, 2, t2);
    BAR;
    MFMA_Q(1, 0);
    VMW(4);
    BAR;
    {
      const char* AbN = (const char*)lds + b1 * 32768;
      const char* BbN = (const char*)lds + 65536 + b1 * 32768;
      READ_A(0, AbN);
      READ_B(0, BbN);
      READ_B(1, BbN);
    }
  }
  VMW(0);  // drain DMA before LDS goes out of scope

  // Epilogue: C/D layout col=l16 (B-frag j), row=quad*4+reg (A-frag i).
#pragma unroll
  for (int j = 0; j < 4; j++) {
    const int col = n0 + wn * 64 + j * 16 + l16;
    const float bv = bias[col];
#pragma unroll
    for (int i = 0; i < 8; i++) {
      const int row = m0 + wm * 128 + i * 16 + quad * 4;
#pragma unroll
      for (int r = 0; r < 4; r++) {
        C[(size_t)(row + r) * N_DIM + col] = acc[i][j][r] + bv;
      }
    }
  }
}

extern "C" void kernel_launch(void* const* d_in, const int* in_sizes, int n_in,
                              void* d_out, int out_size, void* d_ws, size_t ws_size,
                              hipStream_t stream) {
  const float* x  = (const float*)d_in[0];  // [4,2048,4096] fp32
  const float* W  = (const float*)d_in[1];  // [4096,4096] fp32
  const float* b  = (const float*)d_in[2];  // [4096] fp32
  const float* Au = (const float*)d_in[3];  // [8,4096] fp32
  const float* Bu = (const float*)d_in[4];  // [4096,8] fp32
  const float* A0 = (const float*)d_in[5];  // [56,2048] fp32
  const float* B0 = (const float*)d_in[6];  // [2048,56] fp32
  float* out = (float*)d_out;               // [4,2048,4096] fp32

  u16* Xb   = (u16*)d_ws;                                      // 64 MB
  u16* Weff = (u16*)((char*)d_ws + (size_t)64 * 1024 * 1024);  // 32 MB

  cvt_x<<<16384, 256, 0, stream>>>(x, Xb);
  build_weff<<<dim3(4, 256), 256, 0, stream>>>(W, Au, Bu, A0, B0, Weff);
  gemm_bt_bias<<<dim3(512), dim3(512), 0, stream>>>(Xb, Weff, b, out);
}

// Round 5
// 540.177 us; speedup vs baseline: 1.1145x; 1.0201x over previous
//
#include <hip/hip_runtime.h>

typedef unsigned short u16;
typedef __bf16 bf16x8 __attribute__((ext_vector_type(8)));
typedef float f32x4 __attribute__((ext_vector_type(4)));
typedef u16 u16x8 __attribute__((ext_vector_type(8)));

#define M_DIM 8192
#define N_DIM 4096
#define K_DIM 4096
#define BM 256
#define BN 256
#define BK 64
#define NT (K_DIM / BK)  // 64 K-tiles

__device__ __forceinline__ u16 f2b(float f) {
  unsigned int x = __float_as_uint(f);
  unsigned int r = (x + 0x7fffu + ((x >> 16) & 1u)) >> 16;
  return (u16)r;
}

#define GLOAD_LDS16(gp, lp)                                        \
  __builtin_amdgcn_global_load_lds(                                \
      (const __attribute__((address_space(1))) void*)(gp),         \
      (__attribute__((address_space(3))) void*)(lp), 16, 0, 0)

#define BAR __builtin_amdgcn_s_barrier()
// Counted vmem wait + rule-#18 fence (no ds_read hoisted across the wait).
#define VMW(N)                                                     \
  do {                                                             \
    asm volatile("s_waitcnt vmcnt(" #N ")" ::: "memory");          \
    __builtin_amdgcn_sched_barrier(0);                             \
  } while (0)

// ---------------------------------------------------------------------------
// Kernel 0: convert x fp32 -> bf16. 8 elements / thread. (R3-proven)
// ---------------------------------------------------------------------------
__global__ __launch_bounds__(256) void cvt_x(const float* __restrict__ X,
                                             u16* __restrict__ Xb) {
  const size_t t = (size_t)blockIdx.x * 256 + threadIdx.x;
  const f32x4* src = (const f32x4*)X + t * 2;
  f32x4 a = src[0];
  f32x4 b = src[1];
  u16x8 o;
  o[0] = f2b(a[0]); o[1] = f2b(a[1]); o[2] = f2b(a[2]); o[3] = f2b(a[3]);
  o[4] = f2b(b[0]); o[5] = f2b(b[1]); o[6] = f2b(b[2]); o[7] = f2b(b[3]);
  *((u16x8*)Xb + t) = o;
}

// ---------------------------------------------------------------------------
// Kernel 1: Weff build (R3-proven, unchanged)
// ---------------------------------------------------------------------------
__global__ __launch_bounds__(256) void build_weff(
    const float* __restrict__ W, const float* __restrict__ Au,
    const float* __restrict__ Bu, const float* __restrict__ A0,
    const float* __restrict__ B0, u16* __restrict__ Weff) {
  __shared__ float coef[64 * 16];  // coef[r][oi]
  const int t = threadIdx.x;
  const int o0 = blockIdx.y * 16;

#pragma unroll
  for (int j = 0; j < 4; j++) {
    const int idx = t + j * 256;     // 0..1023
    const int r = idx >> 4;          // 0..63
    const int oi = idx & 15;
    const int o = o0 + oi;
    float v;
    if (r < 8) {
      v = Bu[o * 8 + r];
    } else {
      const int rs = r - 8;
      if (o < 2048) {
        v = B0[o * 56 + rs];
      } else {
        const int rr = rs ? (rs - 1) : 55;
        v = B0[(o - 2048) * 56 + rr];
      }
    }
    coef[r * 16 + oi] = v;
  }
  __syncthreads();

  const int d0 = blockIdx.x * 1024 + t * 4;
  const int hi = (d0 >= 2048);
  const int dd = hi ? (d0 - 2048) : d0;

  f32x4 acc[16] = {};

#pragma unroll
  for (int r = 0; r < 8; r++) {
    f32x4 a = *(const f32x4*)(Au + (size_t)r * 4096 + d0);
    const float* cr = &coef[r * 16];
#pragma unroll
    for (int oi = 0; oi < 16; oi++) {
      const float c = cr[oi];
      acc[oi][0] += c * a[0]; acc[oi][1] += c * a[1];
      acc[oi][2] += c * a[2]; acc[oi][3] += c * a[3];
    }
  }
#pragma unroll 4
  for (int rs = 0; rs < 56; rs++) {
    const int rr = hi ? (rs ? (rs - 1) : 55) : rs;
    f32x4 a = *(const f32x4*)(A0 + (size_t)rr * 2048 + dd);
    const float* cr = &coef[(rs + 8) * 16];
#pragma unroll
    for (int oi = 0; oi < 16; oi++) {
      const float c = cr[oi];
      acc[oi][0] += c * a[0]; acc[oi][1] += c * a[1];
      acc[oi][2] += c * a[2]; acc[oi][3] += c * a[3];
    }
  }

#pragma unroll
  for (int oi = 0; oi < 16; oi++) {
    f32x4 w = *(const f32x4*)(W + (size_t)(o0 + oi) * 4096 + d0);
    ushort4 ov;
    ov.x = f2b(acc[oi][0] + w[0]);
    ov.y = f2b(acc[oi][1] + w[1]);
    ov.z = f2b(acc[oi][2] + w[2]);
    ov.w = f2b(acc[oi][3] + w[3]);
    *(ushort4*)(Weff + (size_t)(o0 + oi) * 4096 + d0) = ov;
  }
}

// ---------------------------------------------------------------------------
// Kernel 2: C[m][n] = sum_k Xb[m][k]*Weff[n][k] + bias[n]   (bf16 MFMA, NT)
//
// 256x256, 4 segments/K-tile, reads CO-LOCATED with MFMA clusters so the
// LDS unit and MFMA pipe overlap (R3's layout segregated them -> serial).
// Quadrant order (0,0),(0,1),(1,0),(1,1). Per segment: {DMA stages;
// ds_reads feeding a LATER segment; 16 MFMA; counted VMW; BAR}.
//   S1: stage b(T+1)x4;   read B1(T);   MFMA(0,0); VMW(6) [drains r13(T)]
//   S2: stage r13(T+1);   read A1(T);   MFMA(0,1); VMW(6) [drains r02(T+1)]
//   S3: stage r02(T+2);   read A0(T+1); MFMA(1,0); VMW(4) [drains b(T+1)]
//   S4:                   read B0(T+1); MFMA(1,1)
// Register liveness (no extra banking): bfr1 dead after S4(T-1)->read S1;
// afr1 dead after S4(T-1)->read S2; afr0 dead after S2->read S3(T+1 data);
// bfr0 dead after S3->read S4(T+1 data).
// Ledger (per wave, S1 start): [r13(T),r02(T+1)]=4. S1:+4->8,VMW(6)
// drains r13(T). S2:+2->8,VMW(6) drains r02(T+1). S3:+2->8,VMW(4)
// drains b(T+1). S4: 4 in flight = [r13(T+1),r02(T+2)]. Consistent.
// Margins >=2.5 segs; WAR gaps >=4 barriers; tail T+1/T+2 clamped (data
// garbage but never consumed; addresses in bounds).
// ---------------------------------------------------------------------------
__global__ __launch_bounds__(512, 2) void gemm_bt_bias(
    const u16* __restrict__ X, const u16* __restrict__ Wf,
    const float* __restrict__ bias, float* __restrict__ C) {
  __shared__ __align__(16) u16 lds[65536];  // 128 KiB

  const int tid = threadIdx.x;
  const int wave = tid >> 6;
  const int lane = tid & 63;
  const int wm = wave >> 2;    // 0..1
  const int wn = wave & 3;     // 0..3
  const int quad = lane >> 4;  // 0..3
  const int l16 = lane & 15;

  // T1: XCD-aware swizzle (512 blocks, 64 per XCD, n-fastest).
  const int wgid = ((blockIdx.x & 7) << 6) | (blockIdx.x >> 3);
  const int n0 = (wgid & 15) * BN;  // 16 n-tiles
  const int m0 = (wgid >> 4) * BM;  // 32 m-tiles

  // Staging: linear LDS dest (wave-uniform base + lane*16); global source
  // carries the inverse T2 swizzle: colblock = (l&7)^(l>>3).
  const int srow = lane >> 3;           // 0..7
  const int sq = lane & 7;
  const int scol = ((sq ^ srow) << 3);
  const u16* xg = X + (size_t)(m0 + wave * 8 + srow) * K_DIM + scol;
  const u16* wg = Wf + (size_t)(n0 + wave * 8 + srow) * K_DIM + scol;
  u16* lA = lds + wave * 512;           // wave-uniform
  u16* lB = lds + 32768 + wave * 512;

#define SG_A(b, r, kt)                                                      \
  GLOAD_LDS16(xg + (size_t)(r) * 64 * K_DIM + (size_t)(kt) * BK,            \
              lA + (b) * 16384 + (r) * 4096)
#define SG_B(b, r, kt)                                                      \
  GLOAD_LDS16(wg + (size_t)(r) * 64 * K_DIM + (size_t)(kt) * BK,            \
              lB + (b) * 16384 + (r) * 4096)

  f32x4 acc[8][4] = {};
  bf16x8 afr0[4][2];  // A0-half frags (mi, k)
  bf16x8 afr1[4][2];  // A1-half frags
  bf16x8 bfr0[2][2];  // B0-half frags (ni, k)
  bf16x8 bfr1[2][2];  // B1-half frags

  // T2 read swizzle: phys = (cb*16) ^ ((row&7)<<4); row&7 == l16&7 always.
  const int c0 = (quad << 4) ^ ((l16 & 7) << 4);

#define READ_A(dst, mh, ABASE)                                              \
  do {                                                                      \
    const char* ab_ =                                                       \
        (ABASE) + (size_t)((wm * 128 + (mh) * 64 + l16) * 128);             \
    _Pragma("unroll") for (int mi = 0; mi < 4; mi++) {                      \
      dst[mi][0] = *(const bf16x8*)(ab_ + mi * 2048 + c0);                  \
      dst[mi][1] = *(const bf16x8*)(ab_ + mi * 2048 + (c0 ^ 64));           \
    }                                                                       \
  } while (0)

#define READ_B(dst, nh, BBASE)                                              \
  do {                                                                      \
    const char* bb_ =                                                       \
        (BBASE) + (size_t)((wn * 64 + (nh) * 32 + l16) * 128);              \
    _Pragma("unroll") for (int ni = 0; ni < 2; ni++) {                      \
      dst[ni][0] = *(const bf16x8*)(bb_ + ni * 2048 + c0);                  \
      dst[ni][1] = *(const bf16x8*)(bb_ + ni * 2048 + (c0 ^ 64));           \
    }                                                                       \
  } while (0)

#define MFMA_Q(mh, nh, AF, BF)                                              \
  do {                                                                      \
    __builtin_amdgcn_s_setprio(1);                                          \
    _Pragma("unroll") for (int mi = 0; mi < 4; mi++) {                      \
      _Pragma("unroll") for (int ni = 0; ni < 2; ni++) {                    \
        acc[(mh)*4 + mi][(nh)*2 + ni] =                                     \
            __builtin_amdgcn_mfma_f32_16x16x32_bf16(                        \
                AF[mi][0], BF[ni][0],                                       \
                acc[(mh)*4 + mi][(nh)*2 + ni], 0, 0, 0);                    \
        acc[(mh)*4 + mi][(nh)*2 + ni] =                                     \
            __builtin_amdgcn_mfma_f32_16x16x32_bf16(                        \
                AF[mi][1], BF[ni][1],                                       \
                acc[(mh)*4 + mi][(nh)*2 + ni], 0, 0, 0);                    \
      }                                                                     \
    }                                                                       \
    __builtin_amdgcn_s_setprio(0);                                          \
  } while (0)

  // Prologue: b(0), r02(0), r13(0), r02(1) [10 DMA]. VMW(4) leaves
  // [r13(0), r02(1)] (steady-state entry); b(0)+r02(0) landed ->
  // pre-read A0(0), B0(0).
  SG_B(0, 0, 0); SG_B(0, 1, 0); SG_B(0, 2, 0); SG_B(0, 3, 0);
  SG_A(0, 0, 0); SG_A(0, 2, 0);
  SG_A(0, 1, 0); SG_A(0, 3, 0);
  SG_A(1, 0, 1); SG_A(1, 2, 1);
  VMW(4);
  BAR;
  READ_A(afr0, 0, (const char*)lds);
  READ_B(bfr0, 0, (const char*)lds + 65536);

  for (int T = 0; T < NT; ++T) {
    const int buf = T & 1;
    const int b1 = buf ^ 1;
    const char* Ab = (const char*)lds + buf * 32768;
    const char* AbN = (const char*)lds + b1 * 32768;
    const char* Bb = (const char*)lds + 65536 + buf * 32768;
    const char* BbN = (const char*)lds + 65536 + b1 * 32768;
    const int k1 = (T + 1 < NT) ? T + 1 : NT - 1;
    const int k2 = (T + 2 < NT) ? T + 2 : NT - 1;

    // S1: stage b(T+1); read B1(T); MFMA(0,0); drain r13(T).
    SG_B(b1, 0, k1); SG_B(b1, 1, k1); SG_B(b1, 2, k1); SG_B(b1, 3, k1);
    READ_B(bfr1, 1, Bb);
    MFMA_Q(0, 0, afr0, bfr0);
    VMW(6);
    BAR;

    // S2: stage r13(T+1); read A1(T); MFMA(0,1); drain r02(T+1).
    SG_A(b1, 1, k1); SG_A(b1, 3, k1);
    READ_A(afr1, 1, Ab);
    MFMA_Q(0, 1, afr0, bfr1);
    VMW(6);
    BAR;

    // S3: stage r02(T+2); read A0(T+1); MFMA(1,0); drain b(T+1).
    SG_A(buf, 0, k2); SG_A(buf, 2, k2);
    READ_A(afr0, 0, AbN);
    MFMA_Q(1, 0, afr1, bfr0);
    VMW(4);
    BAR;

    // S4: read B0(T+1); MFMA(1,1).
    READ_B(bfr0, 0, BbN);
    MFMA_Q(1, 1, afr1, bfr1);
    BAR;
  }
  VMW(0);  // drain DMA before LDS goes out of scope

  // Epilogue: C/D layout col=l16 (B-frag j), row=quad*4+reg (A-frag i).
#pragma unroll
  for (int j = 0; j < 4; j++) {
    const int col = n0 + wn * 64 + j * 16 + l16;
    const float bv = bias[col];
#pragma unroll
    for (int i = 0; i < 8; i++) {
      const int row = m0 + wm * 128 + i * 16 + quad * 4;
#pragma unroll
      for (int r = 0; r < 4; r++) {
        C[(size_t)(row + r) * N_DIM + col] = acc[i][j][r] + bv;
      }
    }
  }
}

extern "C" void kernel_launch(void* const* d_in, const int* in_sizes, int n_in,
                              void* d_out, int out_size, void* d_ws, size_t ws_size,
                              hipStream_t stream) {
  const float* x  = (const float*)d_in[0];  // [4,2048,4096] fp32
  const float* W  = (const float*)d_in[1];  // [4096,4096] fp32
  const float* b  = (const float*)d_in[2];  // [4096] fp32
  const float* Au = (const float*)d_in[3];  // [8,4096] fp32
  const float* Bu = (const float*)d_in[4];  // [4096,8] fp32
  const float* A0 = (const float*)d_in[5];  // [56,2048] fp32
  const float* B0 = (const float*)d_in[6];  // [2048,56] fp32
  float* out = (float*)d_out;               // [4,2048,4096] fp32

  u16* Xb   = (u16*)d_ws;                                      // 64 MB
  u16* Weff = (u16*)((char*)d_ws + (size_t)64 * 1024 * 1024);  // 32 MB

  cvt_x<<<16384, 256, 0, stream>>>(x, Xb);
  build_weff<<<dim3(4, 256), 256, 0, stream>>>(W, Au, Bu, A0, B0, Weff);
  gemm_bt_bias<<<dim3(512), dim3(512), 0, stream>>>(Xb, Weff, b, out);
}